// Round 3
// baseline (95.314 us; speedup 1.0000x reference)
//
#include <hip/hip_runtime.h>

#pragma clang fp contract(off)

#define NP 410881  // 641*641

// ---------------------------------------------------------------------------
// Kernel 1: per-slot tables from transformer_class_probs (128 x 134).
// One wave per 8 rows; shuffle-reduce (max, first-index) over 133 cols.
// ---------------------------------------------------------------------------
__global__ __launch_bounds__(1024) void slot_kernel(
    const float* __restrict__ probs, float* __restrict__ cls_pred,
    int* __restrict__ det_idx, unsigned long long* __restrict__ det_mask,
    int* __restrict__ num_det) {
  __shared__ float s_val[128];
  __shared__ int s_arg[128];
  __shared__ int s_tot0;
  int tid = threadIdx.x;
  int wv = tid >> 6, lane = tid & 63;

  float bvv[8];
  int bii[8];
#pragma unroll
  for (int k = 0; k < 8; ++k) {  // preload: 24 outstanding loads per lane
    int r = wv * 8 + k;
    const float* row = probs + r * 134;
    float v0 = row[lane];
    float v1 = row[lane + 64];
    float v2 = (lane < 5) ? row[lane + 128] : -1.0f;
    float bv = v0;
    int bi = lane;
    if (v1 > bv) { bv = v1; bi = lane + 64; }
    if (v2 > bv) { bv = v2; bi = lane + 128; }
    bvv[k] = bv; bii[k] = bi;
  }
#pragma unroll
  for (int k = 0; k < 8; ++k) {
    float bv = bvv[k];
    int bi = bii[k];
#pragma unroll
    for (int off = 32; off; off >>= 1) {  // (max, first-idx) butterfly
      float ov = __shfl_xor(bv, off);
      int oi = __shfl_xor(bi, off);
      if (ov > bv || (ov == bv && oi < bi)) { bv = ov; bi = oi; }
    }
    if (lane == 0) { s_val[wv * 8 + k] = bv; s_arg[wv * 8 + k] = bi; }
  }
  __syncthreads();

  bool flag = false;
  unsigned long long b = 0;
  if (tid < 128) flag = s_val[tid] >= 0.7f;
  if (wv < 2) b = __ballot(flag);  // wave-uniform branch
  if (tid < 128 && lane == 0) {
    det_mask[wv] = b;
    if (wv == 0) s_tot0 = __popcll(b);
  }
  __syncthreads();
  if (tid < 128) {
    int incl = __popcll(b & ((1ull << lane) - 1)) + (flag ? 1 : 0) +
               (wv ? s_tot0 : 0);
    det_idx[tid] = incl - 1;  // cumsum(det)-1
    cls_pred[tid] = (float)s_arg[tid];
    if (tid == 127) *num_det = incl;
  }
}

// ---------------------------------------------------------------------------
// Kernel 2: lanes = pixels. Block of 128 threads covers a 16x16 output
// region; each lane owns a 1x2 x-strip inside one bilinear cell. 5x5 input
// texel neighborhood staged in LDS [cell][132]. Channel loop vectorized:
// 4 channels per iter via 4x ds_read_b128 (DS-pipe was the round-2
// bottleneck at 4x ds_read_b32 per channel).
// ---------------------------------------------------------------------------
__global__ __launch_bounds__(128) void post_kernel(
    const float* __restrict__ logits, const float* __restrict__ ws_cls,
    const int* __restrict__ ws_didx,
    const unsigned long long* __restrict__ ws_mask,
    const int* __restrict__ ws_ndet, float* __restrict__ out) {
#pragma clang fp contract(off)
  __shared__ float tex[25 * 132];
  __shared__ float s_cls[128];
  __shared__ int s_didx[128];
  int tid = threadIdx.x;
  int X0 = blockIdx.x << 4, Y0 = blockIdx.y << 4;

  // lane -> pixel pair
  int strip = tid & 7, py = tid >> 3;
  int cx = strip >> 1, h = strip & 1;
  int cy = py >> 2;
  int xa = X0 + (cx << 2) + (h << 1);
  int y = Y0 + py;

  int ndet = *ws_ndet;  // uniform
  if (ndet == 0) {      // reference zeroes everything when nothing detected
    if (y < 641) {
      if (xa < 641) {
        int i0 = y * 641 + xa;
        out[i0] = 1.0f; out[NP + i0] = 0.f; out[2 * NP + i0] = 0.f; out[3 * NP + i0] = 0.f;
      }
      if (xa + 1 < 641) {
        int i1 = y * 641 + xa + 1;
        out[i1] = 1.0f; out[NP + i1] = 0.f; out[2 * NP + i1] = 0.f; out[3 * NP + i1] = 0.f;
      }
    }
    return;
  }

  // ---- stage 5x5 texels x 128 ch into LDS (transposed to [cell][132]) ----
  int tX = blockIdx.x << 2, tY = blockIdx.y << 2;  // texel origin
  for (int f = tid; f < 800; f += 128) {           // 800 float4 granules
    int r = f / 160;
    int i = f - r * 160;
    int cc = i >> 5, c4 = i & 31;
    int gy = min(tY + r, 160);
    int gx = min(tX + cc, 160);
    float4 v = *(const float4*)(logits + ((gy * 161 + gx) << 7) + (c4 << 2));
    *(float4*)(tex + (r * 5 + cc) * 132 + (c4 << 2)) = v;
  }
  s_cls[tid] = ws_cls[tid];
  s_didx[tid] = ws_didx[tid];
  __syncthreads();

  const float* p0 = tex + (cy * 5 + cx) * 132;  // a00 @ +0, a01 @ +132
  const float* p1 = p0 + 5 * 132;               // a10, a11
  float wy = 0.25f * (float)(py & 3);
  float iwy = 1.0f - wy;
  float wx0 = 0.5f * (float)h;
  float wx1 = wx0 + 0.25f;
  float iwx0 = 1.0f - wx0, iwx1 = 1.0f - wx1;

  float m0 = -INFINITY, m1 = -INFINITY;  // masked max
  int am0 = 0, am1 = 0;                  // masked argmax (first-index)
  float T0 = 0.f, T1 = 0.f;              // sum exp(v) over detected
  bool dp0 = true, dp1 = true;           // detected_pixel

// one channel: reference op order (y-interp then x-interp), contract off
#define CH(A00, A01, A10, A11, CIDX)                                           \
  {                                                                            \
    float r0 = (A00) * iwy + (A10) * wy;                                       \
    float r1 = (A01) * iwy + (A11) * wy;                                       \
    float v0 = r0 * iwx0 + r1 * wx0;                                           \
    float v1 = r0 * iwx1 + r1 * wx1;                                           \
    bool g0 = v0 > m0; m0 = g0 ? v0 : m0; am0 = g0 ? (CIDX) : am0;             \
    bool g1 = v1 > m1; m1 = g1 ? v1 : m1; am1 = g1 ? (CIDX) : am1;             \
    T0 += __expf(v0);                                                          \
    T1 += __expf(v1);                                                          \
  }

  if (ndet == 128) {  // fast path: masked == resized
#pragma unroll 2
    for (int c = 0; c < 128; c += 4) {
      float4 q00 = *(const float4*)(p0 + c);
      float4 q01 = *(const float4*)(p0 + c + 132);
      float4 q10 = *(const float4*)(p1 + c);
      float4 q11 = *(const float4*)(p1 + c + 132);
      CH(q00.x, q01.x, q10.x, q11.x, c + 0);
      CH(q00.y, q01.y, q10.y, q11.y, c + 1);
      CH(q00.z, q01.z, q10.z, q11.z, c + 2);
      CH(q00.w, q01.w, q10.w, q11.w, c + 3);
    }
  } else {  // general: separate raw max; per-channel detection is uniform
    unsigned long long mlo = ws_mask[0], mhi = ws_mask[1];
    float rm0 = -INFINITY, rm1 = -INFINITY;
#pragma unroll 4
    for (int c = 0; c < 128; ++c) {
      float a00 = p0[c], a01 = p0[c + 132];
      float a10 = p1[c], a11 = p1[c + 132];
      float r0 = a00 * iwy + a10 * wy;
      float r1 = a01 * iwy + a11 * wy;
      float v0 = r0 * iwx0 + r1 * wx0;
      float v1 = r0 * iwx1 + r1 * wx1;
      rm0 = fmaxf(rm0, v0);
      rm1 = fmaxf(rm1, v1);
      unsigned long long bit = (c < 64) ? (mlo >> c) : (mhi >> (c - 64));
      if (bit & 1) {  // scalar branch (wave-uniform)
        bool g0 = v0 > m0; m0 = g0 ? v0 : m0; am0 = g0 ? c : am0;
        bool g1 = v1 > m1; m1 = g1 ? v1 : m1; am1 = g1 ? c : am1;
        T0 += __expf(v0);
        T1 += __expf(v1);
      }
    }
    dp0 = (rm0 == m0);
    dp1 = (rm1 == m1);
  }
#undef CH

  // ---- epilogue: conf > 0.4  <=>  exp(m) > 0.4*T  (T > 0, all v bounded)
  float cg0 = ((__expf(m0) > 0.4f * T0) && dp0) ? 1.0f : 0.0f;
  float cg1 = ((__expf(m1) > 0.4f * T1) && dp1) ? 1.0f : 0.0f;
  float sem0 = s_cls[am0], sem1 = s_cls[am1];
  float mid0 = (float)(s_didx[am0] + 1), mid1 = (float)(s_didx[am1] + 1);
  float th0 = (sem0 < 80.f) ? cg0 : 0.f;
  float st0 = cg0 - th0;
  float th1 = (sem1 < 80.f) ? cg1 : 0.f;
  float st1 = cg1 - th1;

  if (y < 641) {
    if (xa < 641) {
      int i0 = y * 641 + xa;
      out[i0] = mid0; out[NP + i0] = sem0; out[2 * NP + i0] = th0; out[3 * NP + i0] = st0;
    }
    if (xa + 1 < 641) {
      int i1 = y * 641 + xa + 1;
      out[i1] = mid1; out[NP + i1] = sem1; out[2 * NP + i1] = th1; out[3 * NP + i1] = st1;
    }
  }
}

extern "C" void kernel_launch(void* const* d_in, const int* in_sizes, int n_in,
                              void* d_out, int out_size, void* d_ws,
                              size_t ws_size, hipStream_t stream) {
  const float* logits = (const float*)d_in[0];  // (161,161,128) f32
  const float* probs = (const float*)d_in[1];   // (128,134) f32
  float* out = (float*)d_out;

  float* ws_f = (float*)d_ws;
  float* cls_pred = ws_f;                                    // 128 f32
  int* det_idx = (int*)(ws_f + 128);                         // 128 i32
  unsigned long long* det_mask = (unsigned long long*)(ws_f + 256);  // 2 u64
  int* num_det = (int*)(ws_f + 260);                         // 1 i32

  slot_kernel<<<1, 1024, 0, stream>>>(probs, cls_pred, det_idx, det_mask,
                                      num_det);

  dim3 grid(41, 41);
  post_kernel<<<grid, 128, 0, stream>>>(logits, cls_pred, det_idx, det_mask,
                                        num_det, out);
}

// Round 4
// 94.481 us; speedup vs baseline: 1.0088x; 1.0088x over previous
//
#include <hip/hip_runtime.h>

#pragma clang fp contract(off)

#define NP 410881  // 641*641

// ---------------------------------------------------------------------------
// Kernel 1: per-slot tables from transformer_class_probs (128 x 134).
// One wave per 8 rows; shuffle-reduce (max, first-index) over 133 cols.
// ---------------------------------------------------------------------------
__global__ __launch_bounds__(1024) void slot_kernel(
    const float* __restrict__ probs, float* __restrict__ cls_pred,
    int* __restrict__ det_idx, unsigned long long* __restrict__ det_mask,
    int* __restrict__ num_det) {
  __shared__ float s_val[128];
  __shared__ int s_arg[128];
  __shared__ int s_tot0;
  int tid = threadIdx.x;
  int wv = tid >> 6, lane = tid & 63;

  float bvv[8];
  int bii[8];
#pragma unroll
  for (int k = 0; k < 8; ++k) {  // preload: 24 outstanding loads per lane
    int r = wv * 8 + k;
    const float* row = probs + r * 134;
    float v0 = row[lane];
    float v1 = row[lane + 64];
    float v2 = (lane < 5) ? row[lane + 128] : -1.0f;
    float bv = v0;
    int bi = lane;
    if (v1 > bv) { bv = v1; bi = lane + 64; }
    if (v2 > bv) { bv = v2; bi = lane + 128; }
    bvv[k] = bv; bii[k] = bi;
  }
#pragma unroll
  for (int k = 0; k < 8; ++k) {
    float bv = bvv[k];
    int bi = bii[k];
#pragma unroll
    for (int off = 32; off; off >>= 1) {  // (max, first-idx) butterfly
      float ov = __shfl_xor(bv, off);
      int oi = __shfl_xor(bi, off);
      if (ov > bv || (ov == bv && oi < bi)) { bv = ov; bi = oi; }
    }
    if (lane == 0) { s_val[wv * 8 + k] = bv; s_arg[wv * 8 + k] = bi; }
  }
  __syncthreads();

  bool flag = false;
  unsigned long long b = 0;
  if (tid < 128) flag = s_val[tid] >= 0.7f;
  if (wv < 2) b = __ballot(flag);  // wave-uniform branch
  if (tid < 128 && lane == 0) {
    det_mask[wv] = b;
    if (wv == 0) s_tot0 = __popcll(b);
  }
  __syncthreads();
  if (tid < 128) {
    int incl = __popcll(b & ((1ull << lane) - 1)) + (flag ? 1 : 0) +
               (wv ? s_tot0 : 0);
    det_idx[tid] = incl - 1;  // cumsum(det)-1
    cls_pred[tid] = (float)s_arg[tid];
    if (tid == 127) *num_det = incl;
  }
}

// ---------------------------------------------------------------------------
// Kernel 2: lanes = pixels. Block of 128 threads covers a 16x16 output
// region; each lane owns a 1x2 x-strip inside one bilinear cell. 5x5 input
// texel neighborhood staged in LDS [cell][132].
// Round-4: 4 independent accumulator streams (channel c -> stream c&3)
// to break the 128-deep serial max/argmax and sum-exp dependency chains
// (round-3 post-mortem: issue rate ~30%, latency-bound).
// ---------------------------------------------------------------------------
__global__ __launch_bounds__(128) void post_kernel(
    const float* __restrict__ logits, const float* __restrict__ ws_cls,
    const int* __restrict__ ws_didx,
    const unsigned long long* __restrict__ ws_mask,
    const int* __restrict__ ws_ndet, float* __restrict__ out) {
#pragma clang fp contract(off)
  __shared__ float tex[25 * 132];
  __shared__ float s_cls[128];
  __shared__ int s_didx[128];
  int tid = threadIdx.x;
  int X0 = blockIdx.x << 4, Y0 = blockIdx.y << 4;

  // lane -> pixel pair
  int strip = tid & 7, py = tid >> 3;
  int cx = strip >> 1, h = strip & 1;
  int cy = py >> 2;
  int xa = X0 + (cx << 2) + (h << 1);
  int y = Y0 + py;

  int ndet = *ws_ndet;  // uniform
  if (ndet == 0) {      // reference zeroes everything when nothing detected
    if (y < 641) {
      if (xa < 641) {
        int i0 = y * 641 + xa;
        out[i0] = 1.0f; out[NP + i0] = 0.f; out[2 * NP + i0] = 0.f; out[3 * NP + i0] = 0.f;
      }
      if (xa + 1 < 641) {
        int i1 = y * 641 + xa + 1;
        out[i1] = 1.0f; out[NP + i1] = 0.f; out[2 * NP + i1] = 0.f; out[3 * NP + i1] = 0.f;
      }
    }
    return;
  }

  // ---- stage 5x5 texels x 128 ch into LDS (transposed to [cell][132]) ----
  int tX = blockIdx.x << 2, tY = blockIdx.y << 2;  // texel origin
  for (int f = tid; f < 800; f += 128) {           // 800 float4 granules
    int r = f / 160;
    int i = f - r * 160;
    int cc = i >> 5, c4 = i & 31;
    int gy = min(tY + r, 160);
    int gx = min(tX + cc, 160);
    float4 v = *(const float4*)(logits + ((gy * 161 + gx) << 7) + (c4 << 2));
    *(float4*)(tex + (r * 5 + cc) * 132 + (c4 << 2)) = v;
  }
  s_cls[tid] = ws_cls[tid];
  s_didx[tid] = ws_didx[tid];
  __syncthreads();

  const float* p0 = tex + (cy * 5 + cx) * 132;  // a00 @ +0, a01 @ +132
  const float* p1 = p0 + 5 * 132;               // a10, a11
  float wy = 0.25f * (float)(py & 3);
  float iwy = 1.0f - wy;
  float wx0 = 0.5f * (float)h;
  float wx1 = wx0 + 0.25f;
  float iwx0 = 1.0f - wx0, iwx1 = 1.0f - wx1;

  float m0 = -INFINITY, m1 = -INFINITY;  // final masked max
  int am0 = 0, am1 = 0;                  // final masked argmax (first-index)
  float T0 = 0.f, T1 = 0.f;              // final sum exp(v) over detected
  bool dp0 = true, dp1 = true;           // detected_pixel

  if (ndet == 128) {  // fast path: masked == resized
    // 4 independent accumulator streams: stream j = channels c with c&3==j
    float ms0[4], ms1[4], Ts0[4], Ts1[4];
    int as0[4], as1[4];
#pragma unroll
    for (int j = 0; j < 4; ++j) {
      ms0[j] = -INFINITY; ms1[j] = -INFINITY;
      Ts0[j] = 0.f; Ts1[j] = 0.f;
      as0[j] = 0; as1[j] = 0;
    }
// one channel into stream J; reference op order, contract off
#define CH(A00, A01, A10, A11, CIDX, J)                                        \
  {                                                                            \
    float r0 = (A00) * iwy + (A10) * wy;                                       \
    float r1 = (A01) * iwy + (A11) * wy;                                       \
    float v0 = r0 * iwx0 + r1 * wx0;                                           \
    float v1 = r0 * iwx1 + r1 * wx1;                                           \
    bool g0 = v0 > ms0[J]; ms0[J] = g0 ? v0 : ms0[J]; as0[J] = g0 ? (CIDX) : as0[J]; \
    bool g1 = v1 > ms1[J]; ms1[J] = g1 ? v1 : ms1[J]; as1[J] = g1 ? (CIDX) : as1[J]; \
    Ts0[J] += __expf(v0);                                                      \
    Ts1[J] += __expf(v1);                                                      \
  }
#pragma unroll 2
    for (int c = 0; c < 128; c += 4) {
      float4 q00 = *(const float4*)(p0 + c);
      float4 q01 = *(const float4*)(p0 + c + 132);
      float4 q10 = *(const float4*)(p1 + c);
      float4 q11 = *(const float4*)(p1 + c + 132);
      CH(q00.x, q01.x, q10.x, q11.x, c + 0, 0);
      CH(q00.y, q01.y, q10.y, q11.y, c + 1, 1);
      CH(q00.z, q01.z, q10.z, q11.z, c + 2, 2);
      CH(q00.w, q01.w, q10.w, q11.w, c + 3, 3);
    }
#undef CH
    // exact merge: global max; on value tie, smallest channel index wins
    m0 = ms0[0]; am0 = as0[0]; m1 = ms1[0]; am1 = as1[0];
#pragma unroll
    for (int j = 1; j < 4; ++j) {
      if (ms0[j] > m0 || (ms0[j] == m0 && as0[j] < am0)) { m0 = ms0[j]; am0 = as0[j]; }
      if (ms1[j] > m1 || (ms1[j] == m1 && as1[j] < am1)) { m1 = ms1[j]; am1 = as1[j]; }
    }
    T0 = (Ts0[0] + Ts0[1]) + (Ts0[2] + Ts0[3]);
    T1 = (Ts1[0] + Ts1[1]) + (Ts1[2] + Ts1[3]);
  } else {  // general: separate raw max; per-channel detection is uniform
    unsigned long long mlo = ws_mask[0], mhi = ws_mask[1];
    float rm0 = -INFINITY, rm1 = -INFINITY;
#pragma unroll 4
    for (int c = 0; c < 128; ++c) {
      float a00 = p0[c], a01 = p0[c + 132];
      float a10 = p1[c], a11 = p1[c + 132];
      float r0 = a00 * iwy + a10 * wy;
      float r1 = a01 * iwy + a11 * wy;
      float v0 = r0 * iwx0 + r1 * wx0;
      float v1 = r0 * iwx1 + r1 * wx1;
      rm0 = fmaxf(rm0, v0);
      rm1 = fmaxf(rm1, v1);
      unsigned long long bit = (c < 64) ? (mlo >> c) : (mhi >> (c - 64));
      if (bit & 1) {  // scalar branch (wave-uniform)
        bool g0 = v0 > m0; m0 = g0 ? v0 : m0; am0 = g0 ? c : am0;
        bool g1 = v1 > m1; m1 = g1 ? v1 : m1; am1 = g1 ? c : am1;
        T0 += __expf(v0);
        T1 += __expf(v1);
      }
    }
    dp0 = (rm0 == m0);
    dp1 = (rm1 == m1);
  }

  // ---- epilogue: conf > 0.4  <=>  exp(m) > 0.4*T  (T > 0, all v bounded)
  float cg0 = ((__expf(m0) > 0.4f * T0) && dp0) ? 1.0f : 0.0f;
  float cg1 = ((__expf(m1) > 0.4f * T1) && dp1) ? 1.0f : 0.0f;
  float sem0 = s_cls[am0], sem1 = s_cls[am1];
  float mid0 = (float)(s_didx[am0] + 1), mid1 = (float)(s_didx[am1] + 1);
  float th0 = (sem0 < 80.f) ? cg0 : 0.f;
  float st0 = cg0 - th0;
  float th1 = (sem1 < 80.f) ? cg1 : 0.f;
  float st1 = cg1 - th1;

  if (y < 641) {
    if (xa < 641) {
      int i0 = y * 641 + xa;
      out[i0] = mid0; out[NP + i0] = sem0; out[2 * NP + i0] = th0; out[3 * NP + i0] = st0;
    }
    if (xa + 1 < 641) {
      int i1 = y * 641 + xa + 1;
      out[i1] = mid1; out[NP + i1] = sem1; out[2 * NP + i1] = th1; out[3 * NP + i1] = st1;
    }
  }
}

extern "C" void kernel_launch(void* const* d_in, const int* in_sizes, int n_in,
                              void* d_out, int out_size, void* d_ws,
                              size_t ws_size, hipStream_t stream) {
  const float* logits = (const float*)d_in[0];  // (161,161,128) f32
  const float* probs = (const float*)d_in[1];   // (128,134) f32
  float* out = (float*)d_out;

  float* ws_f = (float*)d_ws;
  float* cls_pred = ws_f;                                    // 128 f32
  int* det_idx = (int*)(ws_f + 128);                         // 128 i32
  unsigned long long* det_mask = (unsigned long long*)(ws_f + 256);  // 2 u64
  int* num_det = (int*)(ws_f + 260);                         // 1 i32

  slot_kernel<<<1, 1024, 0, stream>>>(probs, cls_pred, det_idx, det_mask,
                                      num_det);

  dim3 grid(41, 41);
  post_kernel<<<grid, 128, 0, stream>>>(logits, cls_pred, det_idx, det_mask,
                                        num_det, out);
}